// Round 19
// baseline (333.699 us; speedup 1.0000x reference)
//
#include <hip/hip_runtime.h>
#include <hip/hip_bf16.h>
#include <math.h>

#define S_LEN 1024
#define HID 256
#define HEADS 8
#define HD 32
#define NLAYER 4
#define TED 256
#define BATCH 4
#define DECAY 0.1f
#define ATT_SCALE 0.17677669529663687f  // 32^-0.5
#define LOG2E 1.4426950408889634f

typedef __bf16 bf8_t __attribute__((ext_vector_type(8)));
typedef float f4_t __attribute__((ext_vector_type(4)));

__device__ __forceinline__ float gelu_f(float x) {
  return 0.5f * x * (1.f + erff(x * 0.70710678118654752f));
}
__device__ __forceinline__ __bf16 f2bf(float f) { return (__bf16)f; }

// ---- boot: weight cvt (4 arrays) + decayed bias + prep stage A, one launch
__global__ __launch_bounds__(256) void k_boot(
    const float* __restrict__ s0, __bf16* __restrict__ d0,
    const float* __restrict__ s1, __bf16* __restrict__ d1,
    const float* __restrict__ s2, __bf16* __restrict__ d2,
    const float* __restrict__ s3, __bf16* __restrict__ d3,
    const float* __restrict__ relb, float* __restrict__ decb_t,
    const float* __restrict__ timev,
    const float* __restrict__ tm_w1, const float* __restrict__ tm_b1,
    const float* __restrict__ query,
    const float* __restrict__ q_w1, const float* __restrict__ q_b1,
    float* __restrict__ te1, float* __restrict__ q1) {
  int bid = blockIdx.x;
  int lane = threadIdx.x & 63;
  if (bid < 1536) {
    const float* s; __bf16* d; int base;
    if (bid < 384)       { s = s0; d = d0; base = bid; }
    else if (bid < 512)  { s = s1; d = d1; base = bid - 384; }
    else if (bid < 1024) { s = s2; d = d2; base = bid - 512; }
    else                 { s = s3; d = d3; base = bid - 1024; }
    int i = (base * 256 + threadIdx.x) * 8;
    float4 a = *(const float4*)(s + i);
    float4 b = *(const float4*)(s + i + 4);
    bf8_t o;
    o[0] = f2bf(a.x); o[1] = f2bf(a.y); o[2] = f2bf(a.z); o[3] = f2bf(a.w);
    o[4] = f2bf(b.x); o[5] = f2bf(b.y); o[6] = f2bf(b.z); o[7] = f2bf(b.w);
    *(bf8_t*)(d + i) = o;
  } else if (bid < 1792) {
    int lb = bid - 1536;
    int l = lb >> 6;
    int i = (lb & 63) * 256 + threadIdx.x;
    if (i < 2047 * 8) {
      int idx = i >> 3, hh = i & 7;
      float dec = __expf(-DECAY * fabsf((float)(idx - 1023)));
      decb_t[(l * 8 + hh) * 2048 + idx] = dec * relb[(size_t)l * 2047 * 8 + i] * LOG2E;
    }
  } else if (bid < 2816) {
    int r = (bid - 1792) * 4 + (threadIdx.x >> 6);
    int o = r & 1023, b = r >> 10;
    float t = timev[b];
    float ev[4];
#pragma unroll
    for (int e = 0; e < 4; e++) {
      int k = lane * 4 + e;
      int i = k & 127;
      float f = __expf(-logf(10000.f) * (float)i / 127.f);
      float a = t * f;
      ev[e] = (k < 128) ? sinf(a) : cosf(a);
    }
    float4 w4 = *(const float4*)(tm_w1 + (size_t)o * 256 + lane * 4);
    float s = ev[0] * w4.x + ev[1] * w4.y + ev[2] * w4.z + ev[3] * w4.w;
#pragma unroll
    for (int off = 32; off; off >>= 1) s += __shfl_xor(s, off);
    if (lane == 0) {
      s += tm_b1[o];
      float sp = (s > 20.f) ? s : log1pf(__expf(s));
      te1[r] = s * tanhf(sp);
    }
  } else {
    int r = (bid - 2816) * 4 + (threadIdx.x >> 6);
    int o = r & 255, b = r >> 8;
    float s = 0.f;
    if (lane < 8) {
      float4 a4 = *(const float4*)(query + b * 32 + lane * 4);
      float4 w4 = *(const float4*)(q_w1 + (size_t)o * 32 + lane * 4);
      s = a4.x * w4.x + a4.y * w4.y + a4.z * w4.z + a4.w * w4.w;
    }
#pragma unroll
    for (int off = 32; off; off >>= 1) s += __shfl_xor(s, off);
    if (lane == 0) q1[r] = gelu_f(s + q_b1[o]);
  }
}

// ---------------- prep stage B: te (K=1024) + qe (K=256), one launch
__global__ __launch_bounds__(256) void k_prep_b(
    const float* __restrict__ te1, const float* __restrict__ tm_w2,
    const float* __restrict__ tm_b2,
    const float* __restrict__ q1, const float* __restrict__ q_w2,
    const float* __restrict__ q_b2,
    float* __restrict__ te, float* __restrict__ qe) {
  int bid = blockIdx.x;
  int lane = threadIdx.x & 63;
  bool iste = bid < 256;
  int r = (iste ? bid : bid - 256) * 4 + (threadIdx.x >> 6);
  int o = r & 255, b = r >> 8;
  int K = iste ? 1024 : 256;
  const float* a = (iste ? te1 : q1) + (size_t)b * K;
  const float* w = (iste ? tm_w2 : q_w2) + (size_t)o * K;
  float s = 0.f;
  for (int k = lane * 4; k < K; k += 256) {
    float4 a4 = *(const float4*)(a + k);
    float4 w4 = *(const float4*)(w + k);
    s += a4.x * w4.x + a4.y * w4.y + a4.z * w4.z + a4.w * w4.w;
  }
#pragma unroll
  for (int off = 32; off; off >>= 1) s += __shfl_xor(s, off);
  if (lane == 0) {
    s += (iste ? tm_b2 : q_b2)[o];
    (iste ? te : qe)[r] = s;
  }
}

// ---- mid: gemv-tt ([0,1024)) + input projection ([1024,5120)), one launch
__global__ __launch_bounds__(256) void k_mid(
    const float* __restrict__ te, const float* __restrict__ t1_w,
    const float* __restrict__ t1_b, float* __restrict__ tt,
    const float* __restrict__ x, const float* __restrict__ in_w,
    const float* __restrict__ in_b, const float* __restrict__ qe,
    float* __restrict__ h) {
  int bid = blockIdx.x;
  if (bid < 1024) {
    int r = bid * 4 + (threadIdx.x >> 6);
    int lane = threadIdx.x & 63;
    int o = r & 255;
    int b = (r >> 8) & 3;
    int g = r >> 10;
    float4 a4 = *(const float4*)(te + (size_t)b * 256 + lane * 4);
    float4 w4 = *(const float4*)(t1_w + ((size_t)(g * 256 + o)) * 256 + lane * 4);
    float s = a4.x * w4.x + a4.y * w4.y + a4.z * w4.z + a4.w * w4.w;
#pragma unroll
    for (int off = 32; off; off >>= 1) s += __shfl_xor(s, off);
    if (lane == 0) tt[r] = gelu_f(s + t1_b[g * 256 + o]);
  } else {
    int row = bid - 1024;
    int b = row >> 10;
    int j = threadIdx.x;
    __shared__ float xr[16];
    if (j < 16) xr[j] = x[row * 16 + j];
    __syncthreads();
    float s = in_b[j] + qe[b * 256 + j];
    const float* w = in_w + j * 16;
#pragma unroll
    for (int i = 0; i < 16; i++) s += xr[i] * w[i];
    h[(size_t)row * 256 + j] = s;
  }
}

// ---------------- tp gemv
__global__ __launch_bounds__(256) void k_t2(
    const float* __restrict__ tt, const float* __restrict__ t2_w,
    const float* __restrict__ t2_b, float* __restrict__ tp) {
  int r = blockIdx.x * 4 + (threadIdx.x >> 6);
  int lane = threadIdx.x & 63;
  int o = r & 255, b = (r >> 8) & 3, g = r >> 10;
  float4 a4 = *(const float4*)(tt + (size_t)(g * 4 + b) * 256 + lane * 4);
  float4 w4 = *(const float4*)(t2_w + (size_t)(g * 256 + o) * 256 + lane * 4);
  float s = a4.x * w4.x + a4.y * w4.y + a4.z * w4.z + a4.w * w4.w;
#pragma unroll
  for (int off = 32; off; off >>= 1) s += __shfl_xor(s, off);
  if (lane == 0) tp[r] = s + t2_b[g * 256 + o];
}

// -------------------------- fused LayerNorm + MFMA GEMM (layer-0 qkv)
__global__ __launch_bounds__(256) void k_gemm_lnf(
    const float* __restrict__ h, const __bf16* __restrict__ W,
    const float* __restrict__ bias, __bf16* __restrict__ Cv,
    const float* __restrict__ tp, const float* __restrict__ lw,
    const float* __restrict__ lb) {
  constexpr int K = 256, BN = 128, NJ = 4, BQ = 2;
  const int N = 768;
  __shared__ __bf16 Al[64 * 264];
  __shared__ __bf16 Bl[2 * BN * 32];
  int tid = threadIdx.x;
  int w = tid >> 6, lane = tid & 63;
  int g = lane >> 4, c = lane & 15;
  int n0 = blockIdx.x * BN, m0 = blockIdx.y * 64;

  int srow = tid >> 2;
  int scol = (tid & 3) * 8;
  int sw = (((tid & 3) ^ ((tid >> 3) & 3))) * 8;
  const __bf16* Wb = W + (size_t)n0 * K + scol;
  bf8_t nB[2][BQ];
#pragma unroll
  for (int sub = 0; sub < 2; sub++)
#pragma unroll
    for (int q = 0; q < BQ; q++)
      nB[sub][q] = *(const bf8_t*)(Wb + (size_t)(q * 64 + srow) * K + sub * 32);

  int sub32 = tid & 31, lrow = tid >> 5;
  int colb = sub32 * 8;
  float4 lw0 = *(const float4*)(lw + colb), lw1 = *(const float4*)(lw + colb + 4);
  float4 lb0 = *(const float4*)(lb + colb), lb1 = *(const float4*)(lb + colb + 4);
  const float* tpr = tp + (m0 >> 10) * 256 + colb;
  float4 tp0 = *(const float4*)tpr, tp1 = *(const float4*)(tpr + 4);
#pragma unroll
  for (int p = 0; p < 8; p++) {
    int row = p * 8 + lrow;
    const float* hr = h + (size_t)(m0 + row) * 256 + colb;
    float4 a = *(const float4*)hr;
    float4 b2 = *(const float4*)(hr + 4);
    a.x += tp0.x; a.y += tp0.y; a.z += tp0.z; a.w += tp0.w;
    b2.x += tp1.x; b2.y += tp1.y; b2.z += tp1.z; b2.w += tp1.w;
    float sum = a.x + a.y + a.z + a.w + b2.x + b2.y + b2.z + b2.w;
    float ss = a.x * a.x + a.y * a.y + a.z * a.z + a.w * a.w +
               b2.x * b2.x + b2.y * b2.y + b2.z * b2.z + b2.w * b2.w;
#pragma unroll
    for (int m = 1; m < 32; m <<= 1) {
      sum += __shfl_xor(sum, m);
      ss += __shfl_xor(ss, m);
    }
    float mean = sum * (1.f / 256.f);
    float var = ss * (1.f / 256.f) - mean * mean;
    float rs = rsqrtf(var + 1e-5f);
    bf8_t o;
    o[0] = f2bf((a.x - mean) * rs * lw0.x + lb0.x);
    o[1] = f2bf((a.y - mean) * rs * lw0.y + lb0.y);
    o[2] = f2bf((a.z - mean) * rs * lw0.z + lb0.z);
    o[3] = f2bf((a.w - mean) * rs * lw0.w + lb0.w);
    o[4] = f2bf((b2.x - mean) * rs * lw1.x + lb1.x);
    o[5] = f2bf((b2.y - mean) * rs * lw1.y + lb1.y);
    o[6] = f2bf((b2.z - mean) * rs * lw1.z + lb1.z);
    o[7] = f2bf((b2.w - mean) * rs * lw1.w + lb1.w);
    *(bf8_t*)&Al[row * 264 + colb] = o;
  }

  int wr = (w >> 1) * 32, wc = (w & 1) * (BN / 2);
  int aseg = ((g ^ ((c >> 1) & 3))) * 8;
  f4_t acc[2][NJ];
#pragma unroll
  for (int i = 0; i < 2; i++)
#pragma unroll
    for (int j = 0; j < NJ; j++) acc[i][j] = (f4_t){0.f, 0.f, 0.f, 0.f};

#pragma unroll
  for (int ph = 0; ph < 4; ph++) {
    __syncthreads();
#pragma unroll
    for (int sub = 0; sub < 2; sub++)
#pragma unroll
      for (int q = 0; q < BQ; q++)
        *(bf8_t*)&Bl[sub * BN * 32 + (q * 64 + srow) * 32 + sw] = nB[sub][q];
    __syncthreads();
    if (ph < 3) {
#pragma unroll
      for (int sub = 0; sub < 2; sub++)
#pragma unroll
        for (int q = 0; q < BQ; q++)
          nB[sub][q] = *(const bf8_t*)(Wb + (size_t)(q * 64 + srow) * K +
                                       (ph + 1) * 64 + sub * 32);
    }
#pragma unroll
    for (int sub = 0; sub < 2; sub++) {
      bf8_t af[2], bfr[NJ];
#pragma unroll
      for (int i = 0; i < 2; i++)
        af[i] = *(const bf8_t*)&Al[(wr + i * 16 + c) * 264 + ph * 64 + sub * 32 + g * 8];
#pragma unroll
      for (int j = 0; j < NJ; j++)
        bfr[j] = *(const bf8_t*)&Bl[sub * BN * 32 + (wc + j * 16 + c) * 32 + aseg];
#pragma unroll
      for (int i = 0; i < 2; i++)
#pragma unroll
        for (int j = 0; j < NJ; j++)
          acc[i][j] = __builtin_amdgcn_mfma_f32_16x16x32_bf16(af[i], bfr[j], acc[i][j], 0, 0, 0);
    }
  }
#pragma unroll
  for (int j = 0; j < NJ; j++) {
    int col = n0 + wc + j * 16 + c;
    float bv = bias[col];
#pragma unroll
    for (int i = 0; i < 2; i++) {
#pragma unroll
      for (int rr = 0; rr < 4; rr++) {
        int row = m0 + wr + i * 16 + 4 * g + rr;
        Cv[(size_t)row * N + col] = f2bf(acc[i][j][rr] + bv);
      }
    }
  }
}

// ------------------------------------ MFMA flash attention (KV tile = 128)
__global__ __launch_bounds__(256) void k_attn(
    const __bf16* __restrict__ qkv, const float* __restrict__ decb_t,
    __bf16* __restrict__ obuf) {
  __shared__ __bf16 Kl[128 * 40];
  __shared__ __bf16 Vt[32 * 136];
  __shared__ __bf16 Pl[4][16 * 136];
  __shared__ float db[1088];

  int tid = threadIdx.x;
  int w = tid >> 6, lane = tid & 63;
  int g = lane >> 4, c = lane & 15;
  int bh = blockIdx.y;
  int b = bh >> 3, hh = bh & 7;
  int q0 = blockIdx.x * 64;

  for (int i = tid; i < 1087; i += 256) db[i] = decb_t[hh * 2048 + q0 + i];

  bf8_t qraw = *(const bf8_t*)(qkv + ((size_t)(b * S_LEN + q0 + w * 16 + c)) * 768 + hh * 32 + 8 * g);
  bf8_t qfrag;
#pragma unroll
  for (int i = 0; i < 8; i++) qfrag[i] = f2bf((float)qraw[i] * (ATT_SCALE * LOG2E));

  float ps_acc[4] = {0.f, 0.f, 0.f, 0.f};
  f4_t o0 = {0.f, 0.f, 0.f, 0.f}, o1 = {0.f, 0.f, 0.f, 0.f};

  int rowb = w * 16 + 4 * g;
  __bf16* Plw = &Pl[w][0];

  int kvr = tid & 127;
  int part = tid >> 7;
  const __bf16* base0 = qkv + ((size_t)(b * S_LEN + kvr)) * 768 + hh * 32 + part * 16;
  bf8_t k8a = *(const bf8_t*)(base0 + 256);
  bf8_t k8b = *(const bf8_t*)(base0 + 264);
  bf8_t v8a = *(const bf8_t*)(base0 + 512);
  bf8_t v8b = *(const bf8_t*)(base0 + 520);

  for (int c0 = 0; c0 < S_LEN; c0 += 128) {
    __syncthreads();
    {
      *(bf8_t*)&Kl[kvr * 40 + part * 16] = k8a;
      *(bf8_t*)&Kl[kvr * 40 + part * 16 + 8] = k8b;
      int d0s = part * 16;
#pragma unroll
      for (int jj = 0; jj < 8; jj++) Vt[(d0s + jj) * 136 + kvr] = v8a[jj];
#pragma unroll
      for (int jj = 0; jj < 8; jj++) Vt[(d0s + 8 + jj) * 136 + kvr] = v8b[jj];
    }
    __syncthreads();
    if (c0 + 128 < S_LEN) {
      const __bf16* basen = base0 + (size_t)(c0 + 128) * 768;
      k8a = *(const bf8_t*)(basen + 256);
      k8b = *(const bf8_t*)(basen + 264);
      v8a = *(const bf8_t*)(basen + 512);
      v8b = *(const bf8_t*)(basen + 520);
    }

    f4_t sc[8];
    f4_t zero4 = {0.f, 0.f, 0.f, 0.f};
    __builtin_amdgcn_s_setprio(1);
#pragma unroll
    for (int j = 0; j < 8; j++) {
      bf8_t kfrag = *(const bf8_t*)&Kl[(j * 16 + c) * 40 + g * 8];
      sc[j] = __builtin_amdgcn_mfma_f32_16x16x32_bf16(qfrag, kfrag, zero4, 0, 0, 0);
    }
    __builtin_amdgcn_s_setprio(0);
#pragma unroll
    for (int j = 0; j < 8; j++) {
      int bidx = rowb + 1023 - (c0 + j * 16 + c);
#pragma unroll
      for (int r = 0; r < 4; r++) {
        float p = exp2f(sc[j][r] + db[bidx + r]);
        ps_acc[r] += p;
        Plw[(4 * g + r) * 136 + j * 16 + c] = f2bf(p);
      }
    }
    __builtin_amdgcn_s_setprio(1);
#pragma unroll
    for (int ss = 0; ss < 4; ss++) {
      bf8_t pa = *(const bf8_t*)&Plw[c * 136 + ss * 32 + g * 8];
      bf8_t v0 = *(const bf8_t*)&Vt[c * 136 + ss * 32 + g * 8];
      bf8_t v1 = *(const bf8_t*)&Vt[(c + 16) * 136 + ss * 32 + g * 8];
      o0 = __builtin_amdgcn_mfma_f32_16x16x32_bf16(pa, v0, o0, 0, 0, 0);
      o1 = __builtin_amdgcn_mfma_f32_16x16x32_bf16(pa, v1, o1, 0, 0, 0);
    }
    __builtin_amdgcn_s_setprio(0);
  }

#pragma unroll
  for (int r = 0; r < 4; r++) {
#pragma unroll
    for (int m = 1; m < 16; m <<= 1) ps_acc[r] += __shfl_xor(ps_acc[r], m);
    float inv = 1.f / ps_acc[r];
    size_t rowg = (size_t)(b * S_LEN + q0 + rowb + r);
    obuf[rowg * 256 + hh * 32 + c] = f2bf(o0[r] * inv);
    obuf[rowg * 256 + hh * 32 + 16 + c] = f2bf(o1[r] * inv);
  }
}

// ---- fused back-half, 8 ROWS/BLOCK (512 blocks -> 2 independent blocks/CU):
// h += ap(obb); LN2; f1+gelu; h += f2(y1);
// NEXT==1: next-layer qkv (LN1 from registers); NEXT==2: final out.
// A-fragment rows 8-15 duplicate rows 0-7 via (c&7); result writes guarded.
template <int NEXT>
__global__ __launch_bounds__(512) void k_back(
    const __bf16* __restrict__ obb, float* __restrict__ h,
    const __bf16* __restrict__ wap, const float* __restrict__ apb,
    const float* __restrict__ n2w, const float* __restrict__ n2b,
    const __bf16* __restrict__ wf1, const float* __restrict__ f1b,
    const __bf16* __restrict__ wf2, const float* __restrict__ f2b,
    const __bf16* __restrict__ wqkvn, const float* __restrict__ qkvbn,
    const float* __restrict__ tpn, const float* __restrict__ n1wn,
    const float* __restrict__ n1bn, __bf16* __restrict__ qkvb,
    const float* __restrict__ out_w, const float* __restrict__ out_b,
    float* __restrict__ out) {
  __shared__ __align__(16) char smem[54528];
  __bf16* Asm = (__bf16*)smem;                 // 8*264 *2B = 4224
  __bf16* Bl  = (__bf16*)(smem + 4224);        // 2 subtiles * 256*32 *2B = 32768
  __bf16* y1l = (__bf16*)(smem + 36992);       // 8*1032 *2B = 16512
  float (*red)[8][2] = (float(*)[8][2])(smem + 53504);  // 8*8*2*4 = 512

  int tid = threadIdx.x;
  int w = tid >> 6, lane = tid & 63;
  int g = lane >> 4, c = lane & 15;
  int m0 = blockIdx.x * 8;
  int srow = tid >> 2;
  int scol = (tid & 3) * 8;
  int sw = (((tid & 3) ^ ((srow >> 1) & 3))) * 8;
  int wc = w * 32;
  int axor = (c >> 1) & 3;
  int boff0 = (wc + c) * 32 + ((g ^ axor)) * 8;
  int boff1 = (wc + 16 + c) * 32 + ((g ^ axor)) * 8;
  int col0 = wc + c, col1 = wc + 16 + c;
  int ca = c & 7;                              // dup A-row index
  f4_t zero4 = {0.f, 0.f, 0.f, 0.f};

  bf8_t buf[2][2];                             // ring-1, 2 subtiles x 2 quarters
  auto PF = [&](const __bf16* base, int K, int ko) {
#pragma unroll
    for (int s = 0; s < 2; s++)
#pragma unroll
      for (int q = 0; q < 2; q++)
        buf[s][q] = *(const bf8_t*)(base + (size_t)(q * 128 + srow) * K + ko + s * 32 + scol);
  };
  auto STAGE = [&]() {
    __syncthreads();
#pragma unroll
    for (int s = 0; s < 2; s++)
#pragma unroll
      for (int q = 0; q < 2; q++)
        *(bf8_t*)&Bl[s * 8192 + (q * 128 + srow) * 32 + sw] = buf[s][q];
    __syncthreads();
  };
  f4_t a0, a1;
  auto mstep = [&](const __bf16* Ab, int AS, int ko) {
#pragma unroll
    for (int s = 0; s < 2; s++) {
      bf8_t af = *(const bf8_t*)&Ab[ca * AS + ko + s * 32 + g * 8];
      bf8_t b0 = *(const bf8_t*)&Bl[s * 8192 + boff0];
      bf8_t b1 = *(const bf8_t*)&Bl[s * 8192 + boff1];
      a0 = __builtin_amdgcn_mfma_f32_16x16x32_bf16(af, b0, a0, 0, 0, 0);
      a1 = __builtin_amdgcn_mfma_f32_16x16x32_bf16(af, b1, a1, 0, 0, 0);
    }
  };

  // ---- prefetch ap phase0; stage obb (8 rows) -> Asm ----
  PF(wap, 256, 0);
  if (tid < 256) {
    int row = tid >> 5, gr = tid & 31;
    *(bf8_t*)&Asm[row * 264 + gr * 8] = *(const bf8_t*)(obb + (size_t)(m0 + row) * 256 + gr * 8);
  }

  // ---- ap GEMM: K=256, 4 phases of 64-k (ring-1) ----
  a0 = zero4; a1 = zero4;
#pragma unroll 1
  for (int ph = 0; ph < 4; ph++) {
    STAGE();
    if (ph < 3) PF(wap, 256, (ph + 1) * 64);
    else PF(wf1, 256, 0);
    mstep(Asm, 264, ph * 64);
  }

  // ---- ap epilogue: residual into h (guarded), LN2 stats ----
  float hn[2][4];
  {
    float b0v = apb[col0], b1v = apb[col1];
    float ps[4], pq[4];
#pragma unroll
    for (int r = 0; r < 4; r++) {
      int row16 = 4 * g + r;
      size_t row = (size_t)(m0 + (row16 & 7));
      float v0 = a0[r] + b0v + h[row * 256 + col0];
      float v1 = a1[r] + b1v + h[row * 256 + col1];
      if (row16 < 8) {
        h[row * 256 + col0] = v0;
        h[row * 256 + col1] = v1;
      }
      hn[0][r] = v0; hn[1][r] = v1;
      ps[r] = v0 + v1;
      pq[r] = v0 * v0 + v1 * v1;
    }
#pragma unroll
    for (int r = 0; r < 4; r++) {
#pragma unroll
      for (int m = 1; m < 16; m <<= 1) {
        ps[r] += __shfl_xor(ps[r], m);
        pq[r] += __shfl_xor(pq[r], m);
      }
    }
    if (c == 0) {
#pragma unroll
      for (int r = 0; r < 4; r++) {
        int row16 = 4 * g + r;
        if (row16 < 8) {
          red[row16][w][0] = ps[r];
          red[row16][w][1] = pq[r];
        }
      }
    }
  }
  __syncthreads();
  {
    float n2w0 = n2w[col0], n2b0 = n2b[col0];
    float n2w1 = n2w[col1], n2b1 = n2b[col1];
#pragma unroll
    for (int r = 0; r < 4; r++) {
      int row16 = 4 * g + r;
      int vrow = row16 & 7;
      float S = 0.f, Q = 0.f;
#pragma unroll
      for (int ww = 0; ww < 8; ww++) { S += red[vrow][ww][0]; Q += red[vrow][ww][1]; }
      float mean = S * (1.f / 256.f);
      float var = Q * (1.f / 256.f) - mean * mean;
      float rs = rsqrtf(var + 1e-5f);
      if (row16 < 8) {
        Asm[row16 * 264 + col0] = f2bf((hn[0][r] - mean) * rs * n2w0 + n2b0);
        Asm[row16 * 264 + col1] = f2bf((hn[1][r] - mean) * rs * n2w1 + n2b1);
      }
    }
  }

  // ---- f1 -> y1l (4 chunks x 4 phases, ring-1) ----
  {
    const __bf16* f1base = wf1;
#pragma unroll 1
    for (int nc = 0; nc < 4; nc++) {
      a0 = zero4; a1 = zero4;
#pragma unroll 1
      for (int ph = 0; ph < 4; ph++) {
        STAGE();
        if (ph < 3) PF(f1base, 256, (ph + 1) * 64);
        else if (nc < 3) PF(f1base + 65536, 256, 0);
        else PF(wf2, 1024, 0);
        mstep(Asm, 264, ph * 64);
      }
      float b0v = f1b[nc * 256 + col0], b1v = f1b[nc * 256 + col1];
#pragma unroll
      for (int r = 0; r < 4; r++) {
        int row16 = 4 * g + r;
        if (row16 < 8) {
          y1l[row16 * 1032 + nc * 256 + col0] = f2bf(gelu_f(a0[r] + b0v));
          y1l[row16 * 1032 + nc * 256 + col1] = f2bf(gelu_f(a1[r] + b1v));
        }
      }
      f1base += 65536;
    }
  }
  __syncthreads();   // y1l complete before cross-wave f2 reads

  // ---- f2 (K=1024, 16 phases, ring-1) ----
  a0 = zero4; a1 = zero4;
#pragma unroll 1
  for (int ph = 0; ph < 16; ph++) {
    STAGE();
    if (ph < 15) PF(wf2, 1024, (ph + 1) * 64);
    else if (NEXT == 1) PF(wqkvn, 256, 0);
    mstep(y1l, 1032, ph * 64);
  }

  // ---- f2 epilogue: final h (guarded) ----
  float hf[2][4];
  {
    float b0v = f2b[col0], b1v = f2b[col1];
#pragma unroll
    for (int r = 0; r < 4; r++) {
      int row16 = 4 * g + r;
      size_t row = (size_t)(m0 + (row16 & 7));
      float v0 = h[row * 256 + col0] + a0[r] + b0v;
      float v1 = h[row * 256 + col1] + a1[r] + b1v;
      if (row16 < 8) {
        h[row * 256 + col0] = v0;
        h[row * 256 + col1] = v1;
      }
      hf[0][r] = v0; hf[1][r] = v1;
    }
  }

  if (NEXT == 1) {
    // ---- LN1 for next layer ----
    int bb = m0 >> 10;
    float t0 = tpn[bb * 256 + col0], t1 = tpn[bb * 256 + col1];
    float v0r[4], v1r[4];
    {
      float ps[4], pq[4];
#pragma unroll
      for (int r = 0; r < 4; r++) {
        float v0 = hf[0][r] + t0, v1 = hf[1][r] + t1;
        v0r[r] = v0; v1r[r] = v1;
        ps[r] = v0 + v1;
        pq[r] = v0 * v0 + v1 * v1;
      }
#pragma unroll
      for (int r = 0; r < 4; r++) {
#pragma unroll
        for (int m = 1; m < 16; m <<= 1) {
          ps[r] += __shfl_xor(ps[r], m);
          pq[r] += __shfl_xor(pq[r], m);
        }
      }
      __syncthreads();  // old red + f2-era LDS reads done
      if (c == 0) {
#pragma unroll
        for (int r = 0; r < 4; r++) {
          int row16 = 4 * g + r;
          if (row16 < 8) {
            red[row16][w][0] = ps[r];
            red[row16][w][1] = pq[r];
          }
        }
      }
    }
    __syncthreads();
    {
      float w0 = n1wn[col0], b0 = n1bn[col0];
      float w1 = n1wn[col1], b1 = n1bn[col1];
#pragma unroll
      for (int r = 0; r < 4; r++) {
        int row16 = 4 * g + r;
        int vrow = row16 & 7;
        float S = 0.f, Q = 0.f;
#pragma unroll
        for (int ww = 0; ww < 8; ww++) { S += red[vrow][ww][0]; Q += red[vrow][ww][1]; }
        float mean = S * (1.f / 256.f);
        float var = Q * (1.f / 256.f) - mean * mean;
        float rs = rsqrtf(var + 1e-5f);
        if (row16 < 8) {
          Asm[row16 * 264 + col0] = f2bf((v0r[r] - mean) * rs * w0 + b0);
          Asm[row16 * 264 + col1] = f2bf((v1r[r] - mean) * rs * w1 + b1);
        }
      }
    }
    __syncthreads();   // new xn visible before qkv ds_reads
    // ---- qkv for next layer: 3 chunks x 4 phases (ring-1) ----
    {
      const __bf16* qbase = wqkvn;
#pragma unroll 1
      for (int nc = 0; nc < 3; nc++) {
        a0 = zero4; a1 = zero4;
#pragma unroll 1
        for (int ph = 0; ph < 4; ph++) {
          STAGE();
          if (ph < 3) PF(qbase, 256, (ph + 1) * 64);
          else if (nc < 2) PF(qbase + 65536, 256, 0);
          mstep(Asm, 264, ph * 64);
        }
        float b0v = qkvbn[nc * 256 + col0], b1v = qkvbn[nc * 256 + col1];
#pragma unroll
        for (int r = 0; r < 4; r++) {
          int row16 = 4 * g + r;
          if (row16 < 8) {
            size_t row = (size_t)(m0 + row16);
            qkvb[row * 768 + nc * 256 + col0] = f2bf(a0[r] + b0v);
            qkvb[row * 768 + nc * 256 + col1] = f2bf(a1[r] + b1v);
          }
        }
        qbase += 65536;
      }
    }
  } else if (NEXT == 2) {
    // ---- final out projection via LDS (overlay Bl) ----
    float* hl = (float*)(smem + 4224);  // 8 x 260 fp32 = 8320B <= 32768
    __syncthreads();                    // all Bl reads done
#pragma unroll
    for (int r = 0; r < 4; r++) {
      int row16 = 4 * g + r;
      if (row16 < 8) {
        hl[row16 * 260 + col0] = hf[0][r];
        hl[row16 * 260 + col1] = hf[1][r];
      }
    }
    __syncthreads();
    if (tid < 128) {
      int r = tid >> 4, cc = tid & 15;
      const float4* hr = (const float4*)&hl[r * 260];
      const float4* w4 = (const float4*)(out_w + cc * 256);
      float s = out_b[cc];
#pragma unroll 8
      for (int k = 0; k < 64; k++) {
        float4 a = hr[k], b = w4[k];
        s += a.x * b.x + a.y * b.y + a.z * b.z + a.w * b.w;
      }
      out[(m0 + r) * 16 + cc] = s;
    }
  }
}

// ------------------------------------------------------------------ host side
extern "C" void kernel_launch(void* const* d_in, const int* in_sizes, int n_in,
                              void* d_out, int out_size, void* d_ws, size_t ws_size,
                              hipStream_t stream) {
  const float* x      = (const float*)d_in[0];
  const float* query  = (const float*)d_in[1];
  const float* timev  = (const float*)d_in[2];
  const float* tm_w1  = (const float*)d_in[3];
  const float* tm_b1  = (const float*)d_in[4];
  const float* tm_w2  = (const float*)d_in[5];
  const float* tm_b2  = (const float*)d_in[6];
  const float* in_w   = (const float*)d_in[7];
  const float* in_b   = (const float*)d_in[8];
  const float* q_w1   = (const float*)d_in[9];
  const float* q_b1   = (const float*)d_in[10];
  const float* q_w2   = (const float*)d_in[11];
  const float* q_b2   = (const float*)d_in[12];
  const float* n1_w   = (const float*)d_in[13];
  const float* n1_b   = (const float*)d_in[14];
  const float* qkv_w  = (const float*)d_in[15];
  const float* qkv_b  = (const float*)d_in[16];
  const float* ap_w   = (const float*)d_in[17];
  const float* ap_b   = (const float*)d_in[18];
  const float* relb   = (const float*)d_in[19];
  const float* n2_w   = (const float*)d_in[20];
  const float* n2_b   = (const float*)d_in[21];
  const float* f1_w   = (const float*)d_in[22];
  const float* f1_b   = (const float*)d_in[23];
  const float* f2_w   = (const float*)d_in[24];
  const float* f2_b   = (const float*)d_in[25];
  const float* t1_w   = (const float*)d_in[26];
  const float* t1_b   = (const float*)d_in[27];
  const float* t2_w   = (const float*)d_in[28];
  const float* t2_b   = (const float*)d_in[29];
  const float* out_w  = (const float*)d_in[30];
  const float* out_b  = (const float*)d_in[31];
  float* out = (float*)d_out;

  float* ws = (float*)d_ws;
  float*  h    = ws;                                   // 1048576 f
  __bf16* qkvb = (__bf16*)(ws + 1572864);              // 4096x768 bf16
  __bf16* obb  = (__bf16*)(ws + 3145728);              // 4096x256 bf16
  __bf16* wqkv = (__bf16*)(ws + 5767168);              // 4x768x256 bf16
  __bf16* wap  = (__bf16*)(ws + 6160384);              // 4x256x256 bf16
  __bf16* wf1  = (__bf16*)(ws + 6291456);              // 4x1024x256 bf16
  __bf16* wf2  = (__bf16*)(ws + 6815744);              // 4x256x1024 bf16
  float* decb  = ws + 7340032;                         // 4x8x2048
  float* qe    = decb + 65536;
  float* tp    = qe + 1024;
  float* te1   = tp + 4096;
  float* te    = te1 + 4096;
  float* q1    = te + 1024;
  float* tt    = q1 + 1024;

  k_boot<<<3072, 256, 0, stream>>>(qkv_w, wqkv, ap_w, wap, f1_w, wf1, f2_w, wf2,
                                   relb, decb, timev, tm_w1, tm_b1,
                                   query, q_w1, q_b1, te1, q1);
  k_prep_b<<<512, 256, 0, stream>>>(te1, tm_w2, tm_b2, q1, q_w2, q_b2, te, qe);
  k_mid<<<5120, 256, 0, stream>>>(te, t1_w, t1_b, tt, x, in_w, in_b, qe, h);
  k_t2<<<1024, 256, 0, stream>>>(tt, t2_w, t2_b, tp);

  // layer-0 qkv
  k_gemm_lnf<<<dim3(6, 64), 256, 0, stream>>>(
      h, wqkv, qkv_b, qkvb, tp, n1_w, n1_b);

  for (int l = 0; l < NLAYER; l++) {
    k_attn<<<dim3(16, 32), 256, 0, stream>>>(qkvb, decb + l * 16384, obb);
    if (l < NLAYER - 1) {
      k_back<1><<<512, 512, 0, stream>>>(
          obb, h, wap + (size_t)l * 65536, ap_b + l * 256,
          n2_w + l * 256, n2_b + l * 256,
          wf1 + (size_t)l * 262144, f1_b + l * 1024,
          wf2 + (size_t)l * 262144, f2_b + l * 256,
          wqkv + (size_t)(l + 1) * 196608, qkv_b + (l + 1) * 768,
          tp + (l + 1) * 1024, n1_w + (l + 1) * 256, n1_b + (l + 1) * 256, qkvb,
          nullptr, nullptr, nullptr);
    } else {
      k_back<2><<<512, 512, 0, stream>>>(
          obb, h, wap + (size_t)l * 65536, ap_b + l * 256,
          n2_w + l * 256, n2_b + l * 256,
          wf1 + (size_t)l * 262144, f1_b + l * 1024,
          wf2 + (size_t)l * 262144, f2_b + l * 256,
          nullptr, nullptr, nullptr, nullptr, nullptr, nullptr,
          out_w, out_b, out);
    }
  }
}

// Round 20
// 265.770 us; speedup vs baseline: 1.2556x; 1.2556x over previous
//
#include <hip/hip_runtime.h>
#include <hip/hip_bf16.h>
#include <math.h>

#define S_LEN 1024
#define HID 256
#define HEADS 8
#define HD 32
#define NLAYER 4
#define TED 256
#define BATCH 4
#define DECAY 0.1f
#define ATT_SCALE 0.17677669529663687f  // 32^-0.5
#define LOG2E 1.4426950408889634f

typedef __bf16 bf8_t __attribute__((ext_vector_type(8)));
typedef float f4_t __attribute__((ext_vector_type(4)));

__device__ __forceinline__ float gelu_f(float x) {
  return 0.5f * x * (1.f + erff(x * 0.70710678118654752f));
}
__device__ __forceinline__ __bf16 f2bf(float f) { return (__bf16)f; }

// ---- boot: weight cvt (4 arrays) + decayed bias + prep stage A, one launch
__global__ __launch_bounds__(256) void k_boot(
    const float* __restrict__ s0, __bf16* __restrict__ d0,
    const float* __restrict__ s1, __bf16* __restrict__ d1,
    const float* __restrict__ s2, __bf16* __restrict__ d2,
    const float* __restrict__ s3, __bf16* __restrict__ d3,
    const float* __restrict__ relb, float* __restrict__ decb_t,
    const float* __restrict__ timev,
    const float* __restrict__ tm_w1, const float* __restrict__ tm_b1,
    const float* __restrict__ query,
    const float* __restrict__ q_w1, const float* __restrict__ q_b1,
    float* __restrict__ te1, float* __restrict__ q1) {
  int bid = blockIdx.x;
  int lane = threadIdx.x & 63;
  if (bid < 1536) {
    const float* s; __bf16* d; int base;
    if (bid < 384)       { s = s0; d = d0; base = bid; }
    else if (bid < 512)  { s = s1; d = d1; base = bid - 384; }
    else if (bid < 1024) { s = s2; d = d2; base = bid - 512; }
    else                 { s = s3; d = d3; base = bid - 1024; }
    int i = (base * 256 + threadIdx.x) * 8;
    float4 a = *(const float4*)(s + i);
    float4 b = *(const float4*)(s + i + 4);
    bf8_t o;
    o[0] = f2bf(a.x); o[1] = f2bf(a.y); o[2] = f2bf(a.z); o[3] = f2bf(a.w);
    o[4] = f2bf(b.x); o[5] = f2bf(b.y); o[6] = f2bf(b.z); o[7] = f2bf(b.w);
    *(bf8_t*)(d + i) = o;
  } else if (bid < 1792) {
    int lb = bid - 1536;
    int l = lb >> 6;
    int i = (lb & 63) * 256 + threadIdx.x;
    if (i < 2047 * 8) {
      int idx = i >> 3, hh = i & 7;
      float dec = __expf(-DECAY * fabsf((float)(idx - 1023)));
      decb_t[(l * 8 + hh) * 2048 + idx] = dec * relb[(size_t)l * 2047 * 8 + i] * LOG2E;
    }
  } else if (bid < 2816) {
    int r = (bid - 1792) * 4 + (threadIdx.x >> 6);
    int o = r & 1023, b = r >> 10;
    float t = timev[b];
    float ev[4];
#pragma unroll
    for (int e = 0; e < 4; e++) {
      int k = lane * 4 + e;
      int i = k & 127;
      float f = __expf(-logf(10000.f) * (float)i / 127.f);
      float a = t * f;
      ev[e] = (k < 128) ? sinf(a) : cosf(a);
    }
    float4 w4 = *(const float4*)(tm_w1 + (size_t)o * 256 + lane * 4);
    float s = ev[0] * w4.x + ev[1] * w4.y + ev[2] * w4.z + ev[3] * w4.w;
#pragma unroll
    for (int off = 32; off; off >>= 1) s += __shfl_xor(s, off);
    if (lane == 0) {
      s += tm_b1[o];
      float sp = (s > 20.f) ? s : log1pf(__expf(s));
      te1[r] = s * tanhf(sp);
    }
  } else {
    int r = (bid - 2816) * 4 + (threadIdx.x >> 6);
    int o = r & 255, b = r >> 8;
    float s = 0.f;
    if (lane < 8) {
      float4 a4 = *(const float4*)(query + b * 32 + lane * 4);
      float4 w4 = *(const float4*)(q_w1 + (size_t)o * 32 + lane * 4);
      s = a4.x * w4.x + a4.y * w4.y + a4.z * w4.z + a4.w * w4.w;
    }
#pragma unroll
    for (int off = 32; off; off >>= 1) s += __shfl_xor(s, off);
    if (lane == 0) q1[r] = gelu_f(s + q_b1[o]);
  }
}

// ---------------- prep stage B: te (K=1024) + qe (K=256), one launch
__global__ __launch_bounds__(256) void k_prep_b(
    const float* __restrict__ te1, const float* __restrict__ tm_w2,
    const float* __restrict__ tm_b2,
    const float* __restrict__ q1, const float* __restrict__ q_w2,
    const float* __restrict__ q_b2,
    float* __restrict__ te, float* __restrict__ qe) {
  int bid = blockIdx.x;
  int lane = threadIdx.x & 63;
  bool iste = bid < 256;
  int r = (iste ? bid : bid - 256) * 4 + (threadIdx.x >> 6);
  int o = r & 255, b = r >> 8;
  int K = iste ? 1024 : 256;
  const float* a = (iste ? te1 : q1) + (size_t)b * K;
  const float* w = (iste ? tm_w2 : q_w2) + (size_t)o * K;
  float s = 0.f;
  for (int k = lane * 4; k < K; k += 256) {
    float4 a4 = *(const float4*)(a + k);
    float4 w4 = *(const float4*)(w + k);
    s += a4.x * w4.x + a4.y * w4.y + a4.z * w4.z + a4.w * w4.w;
  }
#pragma unroll
  for (int off = 32; off; off >>= 1) s += __shfl_xor(s, off);
  if (lane == 0) {
    s += (iste ? tm_b2 : q_b2)[o];
    (iste ? te : qe)[r] = s;
  }
}

// ---- mid: gemv-tt ([0,1024)) + input projection ([1024,5120)), one launch
__global__ __launch_bounds__(256) void k_mid(
    const float* __restrict__ te, const float* __restrict__ t1_w,
    const float* __restrict__ t1_b, float* __restrict__ tt,
    const float* __restrict__ x, const float* __restrict__ in_w,
    const float* __restrict__ in_b, const float* __restrict__ qe,
    float* __restrict__ h) {
  int bid = blockIdx.x;
  if (bid < 1024) {
    int r = bid * 4 + (threadIdx.x >> 6);
    int lane = threadIdx.x & 63;
    int o = r & 255;
    int b = (r >> 8) & 3;
    int g = r >> 10;
    float4 a4 = *(const float4*)(te + (size_t)b * 256 + lane * 4);
    float4 w4 = *(const float4*)(t1_w + ((size_t)(g * 256 + o)) * 256 + lane * 4);
    float s = a4.x * w4.x + a4.y * w4.y + a4.z * w4.z + a4.w * w4.w;
#pragma unroll
    for (int off = 32; off; off >>= 1) s += __shfl_xor(s, off);
    if (lane == 0) tt[r] = gelu_f(s + t1_b[g * 256 + o]);
  } else {
    int row = bid - 1024;
    int b = row >> 10;
    int j = threadIdx.x;
    __shared__ float xr[16];
    if (j < 16) xr[j] = x[row * 16 + j];
    __syncthreads();
    float s = in_b[j] + qe[b * 256 + j];
    const float* w = in_w + j * 16;
#pragma unroll
    for (int i = 0; i < 16; i++) s += xr[i] * w[i];
    h[(size_t)row * 256 + j] = s;
  }
}

// ---------------- tp gemv
__global__ __launch_bounds__(256) void k_t2(
    const float* __restrict__ tt, const float* __restrict__ t2_w,
    const float* __restrict__ t2_b, float* __restrict__ tp) {
  int r = blockIdx.x * 4 + (threadIdx.x >> 6);
  int lane = threadIdx.x & 63;
  int o = r & 255, b = (r >> 8) & 3, g = r >> 10;
  float4 a4 = *(const float4*)(tt + (size_t)(g * 4 + b) * 256 + lane * 4);
  float4 w4 = *(const float4*)(t2_w + (size_t)(g * 256 + o) * 256 + lane * 4);
  float s = a4.x * w4.x + a4.y * w4.y + a4.z * w4.z + a4.w * w4.w;
#pragma unroll
  for (int off = 32; off; off >>= 1) s += __shfl_xor(s, off);
  if (lane == 0) tp[r] = s + t2_b[g * 256 + o];
}

// -------------------------- fused LayerNorm + MFMA GEMM (layer-0 qkv)
__global__ __launch_bounds__(256) void k_gemm_lnf(
    const float* __restrict__ h, const __bf16* __restrict__ W,
    const float* __restrict__ bias, __bf16* __restrict__ Cv,
    const float* __restrict__ tp, const float* __restrict__ lw,
    const float* __restrict__ lb) {
  constexpr int K = 256, BN = 128, NJ = 4, BQ = 2;
  const int N = 768;
  __shared__ __bf16 Al[64 * 264];
  __shared__ __bf16 Bl[2 * BN * 32];
  int tid = threadIdx.x;
  int w = tid >> 6, lane = tid & 63;
  int g = lane >> 4, c = lane & 15;
  int n0 = blockIdx.x * BN, m0 = blockIdx.y * 64;

  int srow = tid >> 2;
  int scol = (tid & 3) * 8;
  int sw = (((tid & 3) ^ ((tid >> 3) & 3))) * 8;
  const __bf16* Wb = W + (size_t)n0 * K + scol;
  bf8_t nB[2][BQ];
#pragma unroll
  for (int sub = 0; sub < 2; sub++)
#pragma unroll
    for (int q = 0; q < BQ; q++)
      nB[sub][q] = *(const bf8_t*)(Wb + (size_t)(q * 64 + srow) * K + sub * 32);

  int sub32 = tid & 31, lrow = tid >> 5;
  int colb = sub32 * 8;
  float4 lw0 = *(const float4*)(lw + colb), lw1 = *(const float4*)(lw + colb + 4);
  float4 lb0 = *(const float4*)(lb + colb), lb1 = *(const float4*)(lb + colb + 4);
  const float* tpr = tp + (m0 >> 10) * 256 + colb;
  float4 tp0 = *(const float4*)tpr, tp1 = *(const float4*)(tpr + 4);
#pragma unroll
  for (int p = 0; p < 8; p++) {
    int row = p * 8 + lrow;
    const float* hr = h + (size_t)(m0 + row) * 256 + colb;
    float4 a = *(const float4*)hr;
    float4 b2 = *(const float4*)(hr + 4);
    a.x += tp0.x; a.y += tp0.y; a.z += tp0.z; a.w += tp0.w;
    b2.x += tp1.x; b2.y += tp1.y; b2.z += tp1.z; b2.w += tp1.w;
    float sum = a.x + a.y + a.z + a.w + b2.x + b2.y + b2.z + b2.w;
    float ss = a.x * a.x + a.y * a.y + a.z * a.z + a.w * a.w +
               b2.x * b2.x + b2.y * b2.y + b2.z * b2.z + b2.w * b2.w;
#pragma unroll
    for (int m = 1; m < 32; m <<= 1) {
      sum += __shfl_xor(sum, m);
      ss += __shfl_xor(ss, m);
    }
    float mean = sum * (1.f / 256.f);
    float var = ss * (1.f / 256.f) - mean * mean;
    float rs = rsqrtf(var + 1e-5f);
    bf8_t o;
    o[0] = f2bf((a.x - mean) * rs * lw0.x + lb0.x);
    o[1] = f2bf((a.y - mean) * rs * lw0.y + lb0.y);
    o[2] = f2bf((a.z - mean) * rs * lw0.z + lb0.z);
    o[3] = f2bf((a.w - mean) * rs * lw0.w + lb0.w);
    o[4] = f2bf((b2.x - mean) * rs * lw1.x + lb1.x);
    o[5] = f2bf((b2.y - mean) * rs * lw1.y + lb1.y);
    o[6] = f2bf((b2.z - mean) * rs * lw1.z + lb1.z);
    o[7] = f2bf((b2.w - mean) * rs * lw1.w + lb1.w);
    *(bf8_t*)&Al[row * 264 + colb] = o;
  }

  int wr = (w >> 1) * 32, wc = (w & 1) * (BN / 2);
  int aseg = ((g ^ ((c >> 1) & 3))) * 8;
  f4_t acc[2][NJ];
#pragma unroll
  for (int i = 0; i < 2; i++)
#pragma unroll
    for (int j = 0; j < NJ; j++) acc[i][j] = (f4_t){0.f, 0.f, 0.f, 0.f};

#pragma unroll
  for (int ph = 0; ph < 4; ph++) {
    __syncthreads();
#pragma unroll
    for (int sub = 0; sub < 2; sub++)
#pragma unroll
      for (int q = 0; q < BQ; q++)
        *(bf8_t*)&Bl[sub * BN * 32 + (q * 64 + srow) * 32 + sw] = nB[sub][q];
    __syncthreads();
    if (ph < 3) {
#pragma unroll
      for (int sub = 0; sub < 2; sub++)
#pragma unroll
        for (int q = 0; q < BQ; q++)
          nB[sub][q] = *(const bf8_t*)(Wb + (size_t)(q * 64 + srow) * K +
                                       (ph + 1) * 64 + sub * 32);
    }
#pragma unroll
    for (int sub = 0; sub < 2; sub++) {
      bf8_t af[2], bfr[NJ];
#pragma unroll
      for (int i = 0; i < 2; i++)
        af[i] = *(const bf8_t*)&Al[(wr + i * 16 + c) * 264 + ph * 64 + sub * 32 + g * 8];
#pragma unroll
      for (int j = 0; j < NJ; j++)
        bfr[j] = *(const bf8_t*)&Bl[sub * BN * 32 + (wc + j * 16 + c) * 32 + aseg];
#pragma unroll
      for (int i = 0; i < 2; i++)
#pragma unroll
        for (int j = 0; j < NJ; j++)
          acc[i][j] = __builtin_amdgcn_mfma_f32_16x16x32_bf16(af[i], bfr[j], acc[i][j], 0, 0, 0);
    }
  }
#pragma unroll
  for (int j = 0; j < NJ; j++) {
    int col = n0 + wc + j * 16 + c;
    float bv = bias[col];
#pragma unroll
    for (int i = 0; i < 2; i++) {
#pragma unroll
      for (int rr = 0; rr < 4; rr++) {
        int row = m0 + wr + i * 16 + 4 * g + rr;
        Cv[(size_t)row * N + col] = f2bf(acc[i][j][rr] + bv);
      }
    }
  }
}

// ------------------------------------ MFMA flash attention (KV tile = 128)
__global__ __launch_bounds__(256) void k_attn(
    const __bf16* __restrict__ qkv, const float* __restrict__ decb_t,
    __bf16* __restrict__ obuf) {
  __shared__ __bf16 Kl[128 * 40];
  __shared__ __bf16 Vt[32 * 136];
  __shared__ __bf16 Pl[4][16 * 136];
  __shared__ float db[1088];

  int tid = threadIdx.x;
  int w = tid >> 6, lane = tid & 63;
  int g = lane >> 4, c = lane & 15;
  int bh = blockIdx.y;
  int b = bh >> 3, hh = bh & 7;
  int q0 = blockIdx.x * 64;

  for (int i = tid; i < 1087; i += 256) db[i] = decb_t[hh * 2048 + q0 + i];

  bf8_t qraw = *(const bf8_t*)(qkv + ((size_t)(b * S_LEN + q0 + w * 16 + c)) * 768 + hh * 32 + 8 * g);
  bf8_t qfrag;
#pragma unroll
  for (int i = 0; i < 8; i++) qfrag[i] = f2bf((float)qraw[i] * (ATT_SCALE * LOG2E));

  float ps_acc[4] = {0.f, 0.f, 0.f, 0.f};
  f4_t o0 = {0.f, 0.f, 0.f, 0.f}, o1 = {0.f, 0.f, 0.f, 0.f};

  int rowb = w * 16 + 4 * g;
  __bf16* Plw = &Pl[w][0];

  int kvr = tid & 127;
  int part = tid >> 7;
  const __bf16* base0 = qkv + ((size_t)(b * S_LEN + kvr)) * 768 + hh * 32 + part * 16;
  bf8_t k8a = *(const bf8_t*)(base0 + 256);
  bf8_t k8b = *(const bf8_t*)(base0 + 264);
  bf8_t v8a = *(const bf8_t*)(base0 + 512);
  bf8_t v8b = *(const bf8_t*)(base0 + 520);

  for (int c0 = 0; c0 < S_LEN; c0 += 128) {
    __syncthreads();
    {
      *(bf8_t*)&Kl[kvr * 40 + part * 16] = k8a;
      *(bf8_t*)&Kl[kvr * 40 + part * 16 + 8] = k8b;
      int d0s = part * 16;
#pragma unroll
      for (int jj = 0; jj < 8; jj++) Vt[(d0s + jj) * 136 + kvr] = v8a[jj];
#pragma unroll
      for (int jj = 0; jj < 8; jj++) Vt[(d0s + 8 + jj) * 136 + kvr] = v8b[jj];
    }
    __syncthreads();
    if (c0 + 128 < S_LEN) {
      const __bf16* basen = base0 + (size_t)(c0 + 128) * 768;
      k8a = *(const bf8_t*)(basen + 256);
      k8b = *(const bf8_t*)(basen + 264);
      v8a = *(const bf8_t*)(basen + 512);
      v8b = *(const bf8_t*)(basen + 520);
    }

    f4_t sc[8];
    f4_t zero4 = {0.f, 0.f, 0.f, 0.f};
    __builtin_amdgcn_s_setprio(1);
#pragma unroll
    for (int j = 0; j < 8; j++) {
      bf8_t kfrag = *(const bf8_t*)&Kl[(j * 16 + c) * 40 + g * 8];
      sc[j] = __builtin_amdgcn_mfma_f32_16x16x32_bf16(qfrag, kfrag, zero4, 0, 0, 0);
    }
    __builtin_amdgcn_s_setprio(0);
#pragma unroll
    for (int j = 0; j < 8; j++) {
      int bidx = rowb + 1023 - (c0 + j * 16 + c);
#pragma unroll
      for (int r = 0; r < 4; r++) {
        float p = exp2f(sc[j][r] + db[bidx + r]);
        ps_acc[r] += p;
        Plw[(4 * g + r) * 136 + j * 16 + c] = f2bf(p);
      }
    }
    __builtin_amdgcn_s_setprio(1);
#pragma unroll
    for (int ss = 0; ss < 4; ss++) {
      bf8_t pa = *(const bf8_t*)&Plw[c * 136 + ss * 32 + g * 8];
      bf8_t v0 = *(const bf8_t*)&Vt[c * 136 + ss * 32 + g * 8];
      bf8_t v1 = *(const bf8_t*)&Vt[(c + 16) * 136 + ss * 32 + g * 8];
      o0 = __builtin_amdgcn_mfma_f32_16x16x32_bf16(pa, v0, o0, 0, 0, 0);
      o1 = __builtin_amdgcn_mfma_f32_16x16x32_bf16(pa, v1, o1, 0, 0, 0);
    }
    __builtin_amdgcn_s_setprio(0);
  }

#pragma unroll
  for (int r = 0; r < 4; r++) {
#pragma unroll
    for (int m = 1; m < 16; m <<= 1) ps_acc[r] += __shfl_xor(ps_acc[r], m);
    float inv = 1.f / ps_acc[r];
    size_t rowg = (size_t)(b * S_LEN + q0 + rowb + r);
    obuf[rowg * 256 + hh * 32 + c] = f2bf(o0[r] * inv);
    obuf[rowg * 256 + hh * 32 + 16 + c] = f2bf(o1[r] * inv);
  }
}

// ---- fused back-half (128-k phases, ring-2, RUNTIME loops to fit I$):
// h += ap(obb); LN2; f1+gelu; h += f2(y1);
// then NEXT==1: qkv of next layer (LN1 from registers); NEXT==2: final out.
template <int NEXT>
__global__ __launch_bounds__(512) void k_back(
    const __bf16* __restrict__ obb, float* __restrict__ h,
    const __bf16* __restrict__ wap, const float* __restrict__ apb,
    const float* __restrict__ n2w, const float* __restrict__ n2b,
    const __bf16* __restrict__ wf1, const float* __restrict__ f1b,
    const __bf16* __restrict__ wf2, const float* __restrict__ f2b,
    const __bf16* __restrict__ wqkvn, const float* __restrict__ qkvbn,
    const float* __restrict__ tpn, const float* __restrict__ n1wn,
    const float* __restrict__ n1bn, __bf16* __restrict__ qkvb,
    const float* __restrict__ out_w, const float* __restrict__ out_b,
    float* __restrict__ out) {
  __shared__ __align__(16) char smem[108032];
  __bf16* Asm = (__bf16*)smem;                 // 16*264 *2B = 8448
  __bf16* Bl  = (__bf16*)(smem + 8448);        // 4 subtiles * 256*32 *2B = 65536
  __bf16* y1l = (__bf16*)(smem + 73984);       // 16*1032 *2B = 33024
  float (*red)[8][2] = (float(*)[8][2])(smem + 107008);  // 1024

  int tid = threadIdx.x;
  int w = tid >> 6, lane = tid & 63;
  int g = lane >> 4, c = lane & 15;
  int m0 = blockIdx.x * 16;
  int srow = tid >> 2;
  int scol = (tid & 3) * 8;
  int sw = (((tid & 3) ^ ((srow >> 1) & 3))) * 8;
  int wc = w * 32;
  int axor = (c >> 1) & 3;
  int boff0 = (wc + c) * 32 + ((g ^ axor)) * 8;
  int boff1 = (wc + 16 + c) * 32 + ((g ^ axor)) * 8;
  int col0 = wc + c, col1 = wc + 16 + c;
  f4_t zero4 = {0.f, 0.f, 0.f, 0.f};

  bf8_t bufA[4][2], bufB[4][2];   // ring-2, statically alternated
  auto PF = [&](bf8_t (&nb)[4][2], const __bf16* base, int K, int ko) {
#pragma unroll
    for (int s = 0; s < 4; s++)
#pragma unroll
      for (int q = 0; q < 2; q++)
        nb[s][q] = *(const bf8_t*)(base + (size_t)(q * 128 + srow) * K + ko + s * 32 + scol);
  };
  auto STAGE = [&](bf8_t (&nb)[4][2]) {
    __syncthreads();
#pragma unroll
    for (int s = 0; s < 4; s++)
#pragma unroll
      for (int q = 0; q < 2; q++)
        *(bf8_t*)&Bl[s * 8192 + (q * 128 + srow) * 32 + sw] = nb[s][q];
    __syncthreads();
  };
  f4_t a0, a1;
  auto mstep = [&](const __bf16* Ab, int AS, int ko) {
#pragma unroll
    for (int s = 0; s < 4; s++) {
      bf8_t af = *(const bf8_t*)&Ab[c * AS + ko + s * 32 + g * 8];
      bf8_t b0 = *(const bf8_t*)&Bl[s * 8192 + boff0];
      bf8_t b1 = *(const bf8_t*)&Bl[s * 8192 + boff1];
      a0 = __builtin_amdgcn_mfma_f32_16x16x32_bf16(af, b0, a0, 0, 0, 0);
      a1 = __builtin_amdgcn_mfma_f32_16x16x32_bf16(af, b1, a1, 0, 0, 0);
    }
  };

  // ---- ring fill: ap phases 0,1; stage obb -> Asm ----
  PF(bufA, wap, 256, 0);
  PF(bufB, wap, 256, 128);
  {
    int row = tid >> 5, gr = tid & 31;
    *(bf8_t*)&Asm[row * 264 + gr * 8] = *(const bf8_t*)(obb + (size_t)(m0 + row) * 256 + gr * 8);
  }

  // ---- ap GEMM (phases 0,1); prefetch f1c0 ----
  a0 = zero4; a1 = zero4;
  STAGE(bufA);
  PF(bufA, wf1, 256, 0);
  mstep(Asm, 264, 0);
  STAGE(bufB);
  PF(bufB, wf1, 256, 128);
  mstep(Asm, 264, 128);

  // ---- ap epilogue: residual into h, LN2 stats ----
  float hn[2][4];
  {
    float b0v = apb[col0], b1v = apb[col1];
    float ps[4], pq[4];
#pragma unroll
    for (int r = 0; r < 4; r++) {
      size_t row = (size_t)(m0 + 4 * g + r);
      float v0 = a0[r] + b0v + h[row * 256 + col0];
      float v1 = a1[r] + b1v + h[row * 256 + col1];
      h[row * 256 + col0] = v0;
      h[row * 256 + col1] = v1;
      hn[0][r] = v0; hn[1][r] = v1;
      ps[r] = v0 + v1;
      pq[r] = v0 * v0 + v1 * v1;
    }
#pragma unroll
    for (int r = 0; r < 4; r++) {
#pragma unroll
      for (int m = 1; m < 16; m <<= 1) {
        ps[r] += __shfl_xor(ps[r], m);
        pq[r] += __shfl_xor(pq[r], m);
      }
    }
    if (c == 0) {
#pragma unroll
      for (int r = 0; r < 4; r++) {
        red[4 * g + r][w][0] = ps[r];
        red[4 * g + r][w][1] = pq[r];
      }
    }
  }
  __syncthreads();
  {
    float n2w0 = n2w[col0], n2b0 = n2b[col0];
    float n2w1 = n2w[col1], n2b1 = n2b[col1];
#pragma unroll
    for (int r = 0; r < 4; r++) {
      int row = 4 * g + r;
      float S = 0.f, Q = 0.f;
#pragma unroll
      for (int ww = 0; ww < 8; ww++) { S += red[row][ww][0]; Q += red[row][ww][1]; }
      float mean = S * (1.f / 256.f);
      float var = Q * (1.f / 256.f) - mean * mean;
      float rs = rsqrtf(var + 1e-5f);
      Asm[row * 264 + col0] = f2bf((hn[0][r] - mean) * rs * n2w0 + n2b0);
      Asm[row * 264 + col1] = f2bf((hn[1][r] - mean) * rs * n2w1 + n2b1);
    }
  }

  // ---- f1 -> y1l (4 chunks x 2 phases); RUNTIME loop, ring-2 prefetch ----
  {
    const __bf16* f1base = wf1;
#pragma unroll 1
    for (int nc = 0; nc < 4; nc++) {
      const __bf16* nb = (nc < 3) ? f1base + 65536 : wf2;
      int nk = (nc < 3) ? 256 : 1024;
      a0 = zero4; a1 = zero4;
      STAGE(bufA);
      PF(bufA, nb, nk, 0);
      mstep(Asm, 264, 0);
      STAGE(bufB);
      PF(bufB, nb, nk, 128);
      mstep(Asm, 264, 128);
      float b0v = f1b[nc * 256 + col0], b1v = f1b[nc * 256 + col1];
#pragma unroll
      for (int r = 0; r < 4; r++) {
        y1l[(4 * g + r) * 1032 + nc * 256 + col0] = f2bf(gelu_f(a0[r] + b0v));
        y1l[(4 * g + r) * 1032 + nc * 256 + col1] = f2bf(gelu_f(a1[r] + b1v));
      }
      f1base += 65536;
    }
  }
  __syncthreads();   // y1l complete before cross-wave f2 reads

  // ---- f2 (K=1024, 8 phases); RUNTIME loop, ring-2 prefetch ----
  a0 = zero4; a1 = zero4;
#pragma unroll 1
  for (int pp = 0; pp < 4; pp++) {
    int ko = pp * 256;
    STAGE(bufA);
    if (pp < 3) PF(bufA, wf2, 1024, ko + 256);
    else if (NEXT == 1) PF(bufA, wqkvn, 256, 0);
    mstep(y1l, 1032, ko);
    STAGE(bufB);
    if (pp < 3) PF(bufB, wf2, 1024, ko + 384);
    else if (NEXT == 1) PF(bufB, wqkvn, 256, 128);
    mstep(y1l, 1032, ko + 128);
  }

  // ---- f2 epilogue: final h of this layer ----
  float hf[2][4];
  {
    float b0v = f2b[col0], b1v = f2b[col1];
#pragma unroll
    for (int r = 0; r < 4; r++) {
      size_t row = (size_t)(m0 + 4 * g + r);
      float v0 = h[row * 256 + col0] + a0[r] + b0v;
      float v1 = h[row * 256 + col1] + a1[r] + b1v;
      h[row * 256 + col0] = v0;
      h[row * 256 + col1] = v1;
      hf[0][r] = v0; hf[1][r] = v1;
    }
  }

  if (NEXT == 1) {
    // ---- LN1 for next layer (from registers) ----
    int bb = m0 >> 10;
    float t0 = tpn[bb * 256 + col0], t1 = tpn[bb * 256 + col1];
    float v0r[4], v1r[4];
    {
      float ps[4], pq[4];
#pragma unroll
      for (int r = 0; r < 4; r++) {
        float v0 = hf[0][r] + t0, v1 = hf[1][r] + t1;
        v0r[r] = v0; v1r[r] = v1;
        ps[r] = v0 + v1;
        pq[r] = v0 * v0 + v1 * v1;
      }
#pragma unroll
      for (int r = 0; r < 4; r++) {
#pragma unroll
        for (int m = 1; m < 16; m <<= 1) {
          ps[r] += __shfl_xor(ps[r], m);
          pq[r] += __shfl_xor(pq[r], m);
        }
      }
      __syncthreads();
      if (c == 0) {
#pragma unroll
        for (int r = 0; r < 4; r++) {
          red[4 * g + r][w][0] = ps[r];
          red[4 * g + r][w][1] = pq[r];
        }
      }
    }
    __syncthreads();
    {
      float w0 = n1wn[col0], b0 = n1bn[col0];
      float w1 = n1wn[col1], b1 = n1bn[col1];
#pragma unroll
      for (int r = 0; r < 4; r++) {
        int row = 4 * g + r;
        float S = 0.f, Q = 0.f;
#pragma unroll
        for (int ww = 0; ww < 8; ww++) { S += red[row][ww][0]; Q += red[row][ww][1]; }
        float mean = S * (1.f / 256.f);
        float var = Q * (1.f / 256.f) - mean * mean;
        float rs = rsqrtf(var + 1e-5f);
        Asm[row * 264 + col0] = f2bf((v0r[r] - mean) * rs * w0 + b0);
        Asm[row * 264 + col1] = f2bf((v1r[r] - mean) * rs * w1 + b1);
      }
    }
    __syncthreads();   // new xn visible before qkv ds_reads
    // ---- qkv GEMM for next layer: 3 chunks x 2 phases; RUNTIME loop ----
    {
      const __bf16* qbase = wqkvn;
#pragma unroll 1
      for (int nc = 0; nc < 3; nc++) {
        a0 = zero4; a1 = zero4;
        STAGE(bufA);
        if (nc < 2) PF(bufA, qbase + 65536, 256, 0);
        mstep(Asm, 264, 0);
        STAGE(bufB);
        if (nc < 2) PF(bufB, qbase + 65536, 256, 128);
        mstep(Asm, 264, 128);
        float b0v = qkvbn[nc * 256 + col0], b1v = qkvbn[nc * 256 + col1];
#pragma unroll
        for (int r = 0; r < 4; r++) {
          size_t row = (size_t)(m0 + 4 * g + r);
          qkvb[row * 768 + nc * 256 + col0] = f2bf(a0[r] + b0v);
          qkvb[row * 768 + nc * 256 + col1] = f2bf(a1[r] + b1v);
        }
        qbase += 65536;
      }
    }
  } else if (NEXT == 2) {
    // ---- final out projection from registers via LDS (overlay Bl) ----
    float* hl = (float*)(smem + 8448);  // 16 x 260 fp32
    __syncthreads();
#pragma unroll
    for (int r = 0; r < 4; r++) {
      int row = 4 * g + r;
      hl[row * 260 + col0] = hf[0][r];
      hl[row * 260 + col1] = hf[1][r];
    }
    __syncthreads();
    if (tid < 256) {
      int r = tid >> 4, cc = tid & 15;
      const float4* hr = (const float4*)&hl[r * 260];
      const float4* w4 = (const float4*)(out_w + cc * 256);
      float s = out_b[cc];
#pragma unroll 8
      for (int k = 0; k < 64; k++) {
        float4 a = hr[k], b = w4[k];
        s += a.x * b.x + a.y * b.y + a.z * b.z + a.w * b.w;
      }
      out[(m0 + r) * 16 + cc] = s;
    }
  }
}

// ------------------------------------------------------------------ host side
extern "C" void kernel_launch(void* const* d_in, const int* in_sizes, int n_in,
                              void* d_out, int out_size, void* d_ws, size_t ws_size,
                              hipStream_t stream) {
  const float* x      = (const float*)d_in[0];
  const float* query  = (const float*)d_in[1];
  const float* timev  = (const float*)d_in[2];
  const float* tm_w1  = (const float*)d_in[3];
  const float* tm_b1  = (const float*)d_in[4];
  const float* tm_w2  = (const float*)d_in[5];
  const float* tm_b2  = (const float*)d_in[6];
  const float* in_w   = (const float*)d_in[7];
  const float* in_b   = (const float*)d_in[8];
  const float* q_w1   = (const float*)d_in[9];
  const float* q_b1   = (const float*)d_in[10];
  const float* q_w2   = (const float*)d_in[11];
  const float* q_b2   = (const float*)d_in[12];
  const float* n1_w   = (const float*)d_in[13];
  const float* n1_b   = (const float*)d_in[14];
  const float* qkv_w  = (const float*)d_in[15];
  const float* qkv_b  = (const float*)d_in[16];
  const float* ap_w   = (const float*)d_in[17];
  const float* ap_b   = (const float*)d_in[18];
  const float* relb   = (const float*)d_in[19];
  const float* n2_w   = (const float*)d_in[20];
  const float* n2_b   = (const float*)d_in[21];
  const float* f1_w   = (const float*)d_in[22];
  const float* f1_b   = (const float*)d_in[23];
  const float* f2_w   = (const float*)d_in[24];
  const float* f2_b   = (const float*)d_in[25];
  const float* t1_w   = (const float*)d_in[26];
  const float* t1_b   = (const float*)d_in[27];
  const float* t2_w   = (const float*)d_in[28];
  const float* t2_b   = (const float*)d_in[29];
  const float* out_w  = (const float*)d_in[30];
  const float* out_b  = (const float*)d_in[31];
  float* out = (float*)d_out;

  float* ws = (float*)d_ws;
  float*  h    = ws;                                   // 1048576 f
  __bf16* qkvb = (__bf16*)(ws + 1572864);              // 4096x768 bf16
  __bf16* obb  = (__bf16*)(ws + 3145728);              // 4096x256 bf16
  __bf16* wqkv = (__bf16*)(ws + 5767168);              // 4x768x256 bf16
  __bf16* wap  = (__bf16*)(ws + 6160384);              // 4x256x256 bf16
  __bf16* wf1  = (__bf16*)(ws + 6291456);              // 4x1024x256 bf16
  __bf16* wf2  = (__bf16*)(ws + 6815744);              // 4x256x1024 bf16
  float* decb  = ws + 7340032;                         // 4x8x2048
  float* qe    = decb + 65536;
  float* tp    = qe + 1024;
  float* te1   = tp + 4096;
  float* te    = te1 + 4096;
  float* q1    = te + 1024;
  float* tt    = q1 + 1024;

  k_boot<<<3072, 256, 0, stream>>>(qkv_w, wqkv, ap_w, wap, f1_w, wf1, f2_w, wf2,
                                   relb, decb, timev, tm_w1, tm_b1,
                                   query, q_w1, q_b1, te1, q1);
  k_prep_b<<<512, 256, 0, stream>>>(te1, tm_w2, tm_b2, q1, q_w2, q_b2, te, qe);
  k_mid<<<5120, 256, 0, stream>>>(te, t1_w, t1_b, tt, x, in_w, in_b, qe, h);
  k_t2<<<1024, 256, 0, stream>>>(tt, t2_w, t2_b, tp);

  // layer-0 qkv
  k_gemm_lnf<<<dim3(6, 64), 256, 0, stream>>>(
      h, wqkv, qkv_b, qkvb, tp, n1_w, n1_b);

  for (int l = 0; l < NLAYER; l++) {
    k_attn<<<dim3(16, 32), 256, 0, stream>>>(qkvb, decb + l * 16384, obb);
    if (l < NLAYER - 1) {
      k_back<1><<<256, 512, 0, stream>>>(
          obb, h, wap + (size_t)l * 65536, ap_b + l * 256,
          n2_w + l * 256, n2_b + l * 256,
          wf1 + (size_t)l * 262144, f1_b + l * 1024,
          wf2 + (size_t)l * 262144, f2_b + l * 256,
          wqkv + (size_t)(l + 1) * 196608, qkv_b + (l + 1) * 768,
          tp + (l + 1) * 1024, n1_w + (l + 1) * 256, n1_b + (l + 1) * 256, qkvb,
          nullptr, nullptr, nullptr);
    } else {
      k_back<2><<<256, 512, 0, stream>>>(
          obb, h, wap + (size_t)l * 65536, ap_b + l * 256,
          n2_w + l * 256, n2_b + l * 256,
          wf1 + (size_t)l * 262144, f1_b + l * 1024,
          wf2 + (size_t)l * 262144, f2_b + l * 256,
          nullptr, nullptr, nullptr, nullptr, nullptr, nullptr,
          out_w, out_b, out);
    }
  }
}